// Round 1
// baseline (873.599 us; speedup 1.0000x reference)
//
#include <hip/hip_runtime.h>

#define BSZ 64
#define SLN 50
#define HSD 256
#define MROW 3200          // BSZ*SLN
#define NOUT 39999         // NN-1
#define SCL  0.0625f       // 1/sqrt(256)

typedef unsigned short u16;
typedef __attribute__((ext_vector_type(8))) short short8;
typedef __attribute__((ext_vector_type(4))) float f32x4;

__device__ __forceinline__ u16 f2bf(float x){
  unsigned u = __float_as_uint(x);
  return (u16)((u + 0x7FFFu + ((u >> 16) & 1u)) >> 16);
}

// ---------------- gather: h0[m][d] = emb[idx[m]][d] ----------------
__global__ __launch_bounds__(256) void k_gather(const int* __restrict__ idx,
                                                const float* __restrict__ emb,
                                                float* __restrict__ h0){
  int m = blockIdx.x, t = threadIdx.x;
  h0[(size_t)m*HSD + t] = emb[(size_t)idx[m]*HSD + t];
}

// -------- generic GEMM: C[m][n] = sum_c X[m][c]*W[n][c] + bias[n] --------
// M%64==0 (grid.x=M/64), N%64==0 (grid.y=N/64), K%16==0
__global__ __launch_bounds__(256) void k_gemm(const float* __restrict__ X, int ldx,
                                              const float* __restrict__ W, int ldw,
                                              const float* __restrict__ bias,
                                              float* __restrict__ C, int ldc, int K){
  __shared__ __align__(16) float As[16][68];
  __shared__ __align__(16) float Bs[16][68];
  const int m0 = blockIdx.x*64, n0 = blockIdx.y*64;
  const int t = threadIdx.x;
  const int tx = t & 15, ty = t >> 4;
  const int lrow = t >> 2, lseg = (t & 3) * 4;
  float acc[4][4] = {};
  for (int k0 = 0; k0 < K; k0 += 16){
    float4 av = *(const float4*)&X[(size_t)(m0+lrow)*ldx + k0 + lseg];
    float4 bv = *(const float4*)&W[(size_t)(n0+lrow)*ldw + k0 + lseg];
    As[lseg+0][lrow]=av.x; As[lseg+1][lrow]=av.y; As[lseg+2][lrow]=av.z; As[lseg+3][lrow]=av.w;
    Bs[lseg+0][lrow]=bv.x; Bs[lseg+1][lrow]=bv.y; Bs[lseg+2][lrow]=bv.z; Bs[lseg+3][lrow]=bv.w;
    __syncthreads();
    #pragma unroll
    for (int kk=0; kk<16; ++kk){
      float4 a = *(const float4*)&As[kk][ty*4];
      float4 b = *(const float4*)&Bs[kk][tx*4];
      acc[0][0] += a.x*b.x; acc[0][1] += a.x*b.y; acc[0][2] += a.x*b.z; acc[0][3] += a.x*b.w;
      acc[1][0] += a.y*b.x; acc[1][1] += a.y*b.y; acc[1][2] += a.y*b.z; acc[1][3] += a.y*b.w;
      acc[2][0] += a.z*b.x; acc[2][1] += a.z*b.y; acc[2][2] += a.z*b.z; acc[2][3] += a.z*b.w;
      acc[3][0] += a.w*b.x; acc[3][1] += a.w*b.y; acc[3][2] += a.w*b.z; acc[3][3] += a.w*b.w;
    }
    __syncthreads();
  }
  #pragma unroll
  for (int i2=0;i2<4;++i2)
    #pragma unroll
    for (int j2=0;j2<4;++j2)
      C[(size_t)(m0+ty*4+i2)*ldc + n0 + tx*4 + j2] = acc[i2][j2] + bias[n0+tx*4+j2];
}

// -------- S0[b,i,j] = SCL*Sq0[b,i]·Sk0[b,j]; T0[b,k,l] = Qt0[b,k]·Kt0[b,l] --------
// proj rows (3200) x 1280: [Sq0 | Sk0 | Qt0 | Kt0 | Ak0]
__global__ __launch_bounds__(256) void k_s0t0(const float* __restrict__ proj,
                                              float* __restrict__ S0,
                                              float* __restrict__ T0){
  int b = blockIdx.x, which = blockIdx.y;
  __shared__ float Lq[50][129];
  __shared__ float Lk[50][129];
  const int offq = which ? 512 : 0;
  const int offk = which ? 768 : 256;
  const float scale = which ? 1.0f : SCL;
  float* out = which ? T0 : S0;
  const int t = threadIdx.x;
  float acc[10];
  #pragma unroll
  for (int z=0;z<10;++z) acc[z]=0.f;
  for (int c0=0;c0<HSD;c0+=128){
    __syncthreads();
    for (int e=t; e<50*128; e+=256){
      int row = e>>7, c = e&127;
      Lq[row][c] = proj[(size_t)(b*SLN+row)*1280 + offq + c0 + c];
      Lk[row][c] = proj[(size_t)(b*SLN+row)*1280 + offk + c0 + c];
    }
    __syncthreads();
    #pragma unroll
    for (int z=0;z<10;++z){
      int p = t + z*256;
      if (p < 2500){
        int i = p/50, j = p - i*50;
        float s = 0.f;
        for (int c=0;c<128;++c) s += Lq[i][c]*Lk[j][c];
        acc[z] += s;
      }
    }
  }
  #pragma unroll
  for (int z=0;z<10;++z){
    int p = t + z*256;
    if (p < 2500) out[(size_t)b*2500 + p] = acc[z]*scale;
  }
}

// -------- stage C: P1[b,r,q,k] = softmax_k(S0[b,q,k]+m1[b,r,q,k]); d1 --------
__global__ __launch_bounds__(256) void k_stageC(const float* __restrict__ S0,
                                                const float* __restrict__ m1,
                                                const float* __restrict__ h0,
                                                float* __restrict__ P1,
                                                float* __restrict__ D123){
  const int blk = blockIdx.x;
  const int b = blk/SLN, r = blk - b*SLN;
  __shared__ float P[50][52];
  const int t = threadIdx.x;
  const float* mblk = m1 + (size_t)blk*2500;
  const float* s0b  = S0 + (size_t)b*2500;
  for (int e=t; e<2500; e+=256){
    int i = e/50, j = e - i*50;
    P[i][j] = s0b[e] + mblk[e];
  }
  __syncthreads();
  {
    int i = t>>2, s = t&3;
    if (i < 50){
      float mx = -1e30f;
      for (int j=s; j<50; j+=4) mx = fmaxf(mx, P[i][j]);
      mx = fmaxf(mx, __shfl_xor(mx,1,64));
      mx = fmaxf(mx, __shfl_xor(mx,2,64));
      float sm = 0.f;
      for (int j=s; j<50; j+=4){ float e_ = __expf(P[i][j]-mx); P[i][j]=e_; sm+=e_; }
      sm += __shfl_xor(sm,1,64);
      sm += __shfl_xor(sm,2,64);
      float inv = 1.0f/sm;
      for (int j=s; j<50; j+=4) P[i][j] *= inv;
    }
  }
  __syncthreads();
  float* pout = P1 + (size_t)blk*2500;
  for (int e=t; e<2500; e+=256){
    int i = e/50, j = e - i*50;
    pout[e] = P[i][j];
  }
  float acc = 0.f;
  for (int j=0;j<50;++j) acc += P[r][j]*h0[(size_t)(b*SLN+j)*HSD + t];
  D123[(size_t)blk*768 + t] = acc;   // d1
}

// -------- stage D: sim2 = W·T0·W^T + m2; P2=softmax; V2=P2·W; d2 --------
// W[i][j] = P1[b, i, r, j]
__global__ __launch_bounds__(256) void k_stageD(const float* __restrict__ P1,
                                                const float* __restrict__ T0,
                                                const float* __restrict__ m2,
                                                const float* __restrict__ h0,
                                                float* __restrict__ V2buf,
                                                float* __restrict__ D123){
  const int blk = blockIdx.x;
  const int b = blk/SLN, r = blk - b*SLN;
  __shared__ float W [50][52];
  __shared__ float Wt[50][52];
  __shared__ float T [50][52];
  __shared__ float tm[50][52];
  __shared__ float S [50][52];
  __shared__ float V2r[50];
  const int t = threadIdx.x;
  for (int e=t; e<2500; e+=256){
    int i = e/50, j = e - i*50;
    float w = P1[((size_t)(b*SLN+i)*SLN + r)*SLN + j];
    W[i][j] = w; Wt[j][i] = w;
    T[i][j] = T0[(size_t)b*2500 + e];
  }
  __syncthreads();
  for (int e=t; e<2500; e+=256){
    int i = e/50, l = e - i*50;
    float s = 0.f;
    for (int k=0;k<50;++k) s += W[i][k]*T[k][l];
    tm[i][l] = s;
  }
  __syncthreads();
  const float* mblk = m2 + (size_t)blk*2500;
  for (int e=t; e<2500; e+=256){
    int i = e/50, j = e - i*50;
    float s = 0.f;
    for (int l=0;l<50;++l) s += tm[i][l]*Wt[l][j];
    S[i][j] = s + mblk[e];
  }
  __syncthreads();
  {
    int i = t>>2, sl = t&3;
    if (i < 50){
      float mx = -1e30f;
      for (int j=sl; j<50; j+=4) mx = fmaxf(mx, S[i][j]);
      mx = fmaxf(mx, __shfl_xor(mx,1,64));
      mx = fmaxf(mx, __shfl_xor(mx,2,64));
      float sm = 0.f;
      for (int j=sl; j<50; j+=4){ float e_ = __expf(S[i][j]-mx); S[i][j]=e_; sm+=e_; }
      sm += __shfl_xor(sm,1,64);
      sm += __shfl_xor(sm,2,64);
      float inv = 1.0f/sm;
      for (int j=sl; j<50; j+=4) S[i][j] *= inv;
    }
  }
  __syncthreads();
  float* vout = V2buf + (size_t)blk*2500;
  for (int e=t; e<2500; e+=256){
    int q = e/50, j = e - q*50;
    float s = 0.f;
    for (int k=0;k<50;++k) s += S[q][k]*W[k][j];
    vout[e] = s;
    if (q == r) V2r[j] = s;
  }
  __syncthreads();
  float acc = 0.f;
  for (int j=0;j<50;++j) acc += V2r[j]*h0[(size_t)(b*SLN+j)*HSD + t];
  D123[(size_t)blk*768 + 256 + t] = acc;  // d2
}

// -------- stage E: sim3[k] = SCL*V2[b,k][i,:]·u + m3[b,i,i,k]; d3 --------
__global__ __launch_bounds__(256) void k_stageE(const float* __restrict__ q3d,
                                                const float* __restrict__ proj,
                                                const float* __restrict__ V2buf,
                                                const float* __restrict__ m3,
                                                const float* __restrict__ h0,
                                                float* __restrict__ D123){
  const int blk = blockIdx.x;
  const int b = blk/SLN, i = blk - b*SLN;
  __shared__ float qr[256];
  __shared__ float u[50];
  __shared__ float V[50][52];
  __shared__ float P3[52];
  __shared__ float w3[52];
  const int t = threadIdx.x;
  qr[t] = q3d[(size_t)blk*HSD + t];
  __syncthreads();
  if (t < 200){                       // u[j] = Ak0[b,j]·q3d[b,i]
    int j = t>>2, s = t&3;
    const float* ak = proj + (size_t)(b*SLN+j)*1280 + 1024 + s*64;
    float p = 0.f;
    for (int q=0;q<64;q+=4){
      float4 v = *(const float4*)&ak[q];
      const float* qq = &qr[s*64 + q];
      p += v.x*qq[0] + v.y*qq[1] + v.z*qq[2] + v.w*qq[3];
    }
    p += __shfl_xor(p,1,64); p += __shfl_xor(p,2,64);
    if (s==0) u[j] = p;
  }
  for (int e=t; e<2500; e+=256){
    int k = e/50, j = e - k*50;
    V[k][j] = V2buf[((size_t)(b*SLN+k)*SLN + i)*SLN + j];
  }
  __syncthreads();
  if (t < 200){                       // sim3
    int k = t>>2, s = t&3;
    float p = 0.f;
    for (int j=s; j<50; j+=4) p += V[k][j]*u[j];
    p += __shfl_xor(p,1,64); p += __shfl_xor(p,2,64);
    if (s==0) P3[k] = p*SCL + m3[((size_t)(b*SLN+i)*SLN + i)*SLN + k];
  }
  __syncthreads();
  if (t < 64){                        // softmax over 50
    float v = (t<50) ? P3[t] : -1e30f;
    float mx = v;
    for (int d=1; d<64; d<<=1) mx = fmaxf(mx, __shfl_xor(mx,d,64));
    float e_ = (t<50) ? __expf(v-mx) : 0.f;
    float sm = e_;
    for (int d=1; d<64; d<<=1) sm += __shfl_xor(sm,d,64);
    if (t<50) P3[t] = e_/sm;
  }
  __syncthreads();
  if (t < 200){                       // w3[j] = sum_k P3[k]*V[k][j]
    int j = t>>2, s = t&3;
    float p = 0.f;
    for (int k=s; k<50; k+=4) p += P3[k]*V[k][j];
    p += __shfl_xor(p,1,64); p += __shfl_xor(p,2,64);
    if (s==0) w3[j] = p;
  }
  __syncthreads();
  float acc = 0.f;
  for (int j=0;j<50;++j) acc += w3[j]*h0[(size_t)(b*SLN+j)*HSD + t];
  D123[(size_t)blk*768 + 512 + t] = acc;  // d3
}

// -------- row L2-normalize + cast to bf16; one wave per row --------
__global__ __launch_bounds__(256) void k_norm(const float* __restrict__ X,
                                              u16* __restrict__ out,
                                              int rows, int rowOffsetIn){
  int row = blockIdx.x*4 + (threadIdx.x>>6);
  if (row >= rows) return;
  int lane = threadIdx.x & 63;
  const float* x = X + (size_t)(row + rowOffsetIn)*HSD;
  float4 v = *(const float4*)&x[lane*4];
  float ss = v.x*v.x + v.y*v.y + v.z*v.z + v.w*v.w;
  for (int d=1; d<64; d<<=1) ss += __shfl_xor(ss,d,64);
  float rn = rsqrtf(ss);
  ushort4 o;
  o.x = f2bf(v.x*rn); o.y = f2bf(v.y*rn); o.z = f2bf(v.z*rn); o.w = f2bf(v.w*rn);
  *(ushort4*)&out[(size_t)row*HSD + lane*4] = o;
}

// -------- scores: out[m][n] = sum_k A[m,k]*B[n,k]  (bf16 MFMA) --------
// grid (200, 157): block = 16 M-rows x 256 N-cols; 4 waves x (16x64)
__global__ __launch_bounds__(256) void k_scores(const u16* __restrict__ A,
                                                const u16* __restrict__ Bn,
                                                float* __restrict__ out){
  __shared__ __align__(16) u16 At[16][264];
  const int m0 = blockIdx.x*16;
  const int nb = blockIdx.y*256;
  const int t = threadIdx.x;
  {
    int r = t>>4, c0 = (t&15)*16;
    const u16* src = &A[(size_t)(m0+r)*HSD + c0];
    u16* dst = &At[r][c0];
    *(uint4*)dst       = *(const uint4*)src;
    *(uint4*)(dst + 8) = *(const uint4*)(src + 8);
  }
  __syncthreads();
  const int lane = t & 63, wv = t >> 6;
  const int n0w = nb + wv*64;
  const int nj = lane & 15;
  const int kblk = (lane >> 4) * 8;
  f32x4 acc[4] = {{0,0,0,0},{0,0,0,0},{0,0,0,0},{0,0,0,0}};
  #pragma unroll
  for (int kk=0; kk<8; ++kk){
    short8 af = *(const short8*)&At[nj][kk*32 + kblk];
    #pragma unroll
    for (int nt=0; nt<4; ++nt){
      int n = n0w + nt*16 + nj;
      int nc = (n < NOUT) ? n : (NOUT-1);
      short8 bf = *(const short8*)&Bn[(size_t)nc*HSD + kk*32 + kblk];
      acc[nt] = __builtin_amdgcn_mfma_f32_16x16x32_bf16(af, bf, acc[nt], 0, 0, 0);
    }
  }
  const int mrow = m0 + (lane>>4)*4;
  #pragma unroll
  for (int nt=0; nt<4; ++nt){
    int n = n0w + nt*16 + nj;
    if (n < NOUT){
      #pragma unroll
      for (int rr=0; rr<4; ++rr)
        out[(size_t)(mrow+rr)*NOUT + n] = acc[nt][rr];
    }
  }
}

extern "C" void kernel_launch(void* const* d_in, const int* in_sizes, int n_in,
                              void* d_out, int out_size, void* d_ws, size_t ws_size,
                              hipStream_t stream){
  const int*   idx   = (const int*)  d_in[0];
  const float* m1    = (const float*)d_in[1];
  const float* m2    = (const float*)d_in[2];
  const float* m3    = (const float*)d_in[3];
  const float* emb   = (const float*)d_in[4];
  const float* sq_w  = (const float*)d_in[5];
  const float* sq_b  = (const float*)d_in[6];
  const float* sk_w  = (const float*)d_in[7];
  const float* sk_b  = (const float*)d_in[8];
  const float* tq_w  = (const float*)d_in[9];
  const float* tq_b  = (const float*)d_in[10];
  const float* tk_w  = (const float*)d_in[11];
  const float* tk_b  = (const float*)d_in[12];
  const float* aq_w  = (const float*)d_in[13];
  const float* aq_b  = (const float*)d_in[14];
  const float* ak_w  = (const float*)d_in[15];
  const float* ak_b  = (const float*)d_in[16];
  const float* cat_w = (const float*)d_in[17];
  const float* cat_b = (const float*)d_in[18];
  float* out = (float*)d_out;

  float* ws = (float*)d_ws;
  size_t off = 0;
  float* h0   = ws + off; off += (size_t)MROW*HSD;        // 819200
  float* proj = ws + off; off += (size_t)MROW*1280;       // Sq0|Sk0|Qt0|Kt0|Ak0
  float* Wst  = ws + off; off += (size_t)1280*HSD;
  float* bst  = ws + off; off += 1280;
  float* S0   = ws + off; off += (size_t)BSZ*2500;
  float* T0   = ws + off; off += (size_t)BSZ*2500;
  float* P1   = ws + off; off += (size_t)MROW*2500;
  float* V2   = ws + off; off += (size_t)MROW*2500;
  float* D123 = ws + off; off += (size_t)MROW*768;
  float* q3d  = ws + off; off += (size_t)MROW*HSD;
  float* a32  = ws + off; off += (size_t)MROW*HSD;
  u16*   abf  = (u16*)(ws + off); off += (size_t)MROW*HSD/2;
  u16*   bnf  = (u16*)(ws + off); off += ((size_t)NOUT*HSD+1)/2;
  (void)ws_size; (void)in_sizes; (void)n_in; (void)out_size;

  // stack the 5 projection weights/biases used on h0
  hipMemcpyAsync(Wst + 0*65536, sq_w, 65536*sizeof(float), hipMemcpyDeviceToDevice, stream);
  hipMemcpyAsync(Wst + 1*65536, sk_w, 65536*sizeof(float), hipMemcpyDeviceToDevice, stream);
  hipMemcpyAsync(Wst + 2*65536, tq_w, 65536*sizeof(float), hipMemcpyDeviceToDevice, stream);
  hipMemcpyAsync(Wst + 3*65536, tk_w, 65536*sizeof(float), hipMemcpyDeviceToDevice, stream);
  hipMemcpyAsync(Wst + 4*65536, ak_w, 65536*sizeof(float), hipMemcpyDeviceToDevice, stream);
  hipMemcpyAsync(bst + 0*256, sq_b, 256*sizeof(float), hipMemcpyDeviceToDevice, stream);
  hipMemcpyAsync(bst + 1*256, sk_b, 256*sizeof(float), hipMemcpyDeviceToDevice, stream);
  hipMemcpyAsync(bst + 2*256, tq_b, 256*sizeof(float), hipMemcpyDeviceToDevice, stream);
  hipMemcpyAsync(bst + 3*256, tk_b, 256*sizeof(float), hipMemcpyDeviceToDevice, stream);
  hipMemcpyAsync(bst + 4*256, ak_b, 256*sizeof(float), hipMemcpyDeviceToDevice, stream);

  k_gather<<<MROW, 256, 0, stream>>>(idx, emb, h0);
  k_gemm  <<<dim3(50,20), 256, 0, stream>>>(h0, HSD, Wst, HSD, bst, proj, 1280, HSD);
  k_s0t0  <<<dim3(BSZ,2), 256, 0, stream>>>(proj, S0, T0);
  k_stageC<<<MROW, 256, 0, stream>>>(S0, m1, h0, P1, D123);
  k_stageD<<<MROW, 256, 0, stream>>>(P1, T0, m2, h0, V2, D123);
  k_gemm  <<<dim3(50,4), 256, 0, stream>>>(D123+256, 768, aq_w, HSD, aq_b, q3d, HSD, HSD);
  k_stageE<<<MROW, 256, 0, stream>>>(q3d, proj, V2, m3, h0, D123);
  k_gemm  <<<dim3(50,4), 256, 0, stream>>>(D123, 768, cat_w, 768, cat_b, a32, HSD, 768);
  k_norm  <<<MROW/4, 256, 0, stream>>>(a32, abf, MROW, 0);
  k_norm  <<<10000, 256, 0, stream>>>(emb, bnf, NOUT, 1);
  k_scores<<<dim3(200,157), 256, 0, stream>>>(abf, bnf, out);
}

// Round 2
// 668.226 us; speedup vs baseline: 1.3073x; 1.3073x over previous
//
#include <hip/hip_runtime.h>

#define BSZ 64
#define SLN 50
#define HSD 256
#define MROW 3200          // BSZ*SLN
#define NOUT 39999         // NN-1
#define SCL  0.0625f       // 1/sqrt(256)

typedef unsigned short u16;
typedef __attribute__((ext_vector_type(8))) short short8;
typedef __attribute__((ext_vector_type(4))) float f32x4;

typedef __attribute__((address_space(1))) const unsigned int guint;
typedef __attribute__((address_space(3))) unsigned int luint;

__device__ __forceinline__ u16 f2bf(float x){
  unsigned u = __float_as_uint(x);
  return (u16)((u + 0x7FFFu + ((u >> 16) & 1u)) >> 16);
}

// ---------------- gather: h0[m][d] = emb[idx[m]][d] ----------------
__global__ __launch_bounds__(256) void k_gather(const int* __restrict__ idx,
                                                const float* __restrict__ emb,
                                                float* __restrict__ h0){
  int m = blockIdx.x, t = threadIdx.x;
  h0[(size_t)m*HSD + t] = emb[(size_t)idx[m]*HSD + t];
}

// -------- generic GEMM: C[m][n] = sum_c X[m][c]*W[n][c] + bias[n] --------
__global__ __launch_bounds__(256) void k_gemm(const float* __restrict__ X, int ldx,
                                              const float* __restrict__ W, int ldw,
                                              const float* __restrict__ bias,
                                              float* __restrict__ C, int ldc, int K){
  __shared__ __align__(16) float As[16][68];
  __shared__ __align__(16) float Bs[16][68];
  const int m0 = blockIdx.x*64, n0 = blockIdx.y*64;
  const int t = threadIdx.x;
  const int tx = t & 15, ty = t >> 4;
  const int lrow = t >> 2, lseg = (t & 3) * 4;
  float acc[4][4] = {};
  for (int k0 = 0; k0 < K; k0 += 16){
    float4 av = *(const float4*)&X[(size_t)(m0+lrow)*ldx + k0 + lseg];
    float4 bv = *(const float4*)&W[(size_t)(n0+lrow)*ldw + k0 + lseg];
    As[lseg+0][lrow]=av.x; As[lseg+1][lrow]=av.y; As[lseg+2][lrow]=av.z; As[lseg+3][lrow]=av.w;
    Bs[lseg+0][lrow]=bv.x; Bs[lseg+1][lrow]=bv.y; Bs[lseg+2][lrow]=bv.z; Bs[lseg+3][lrow]=bv.w;
    __syncthreads();
    #pragma unroll
    for (int kk=0; kk<16; ++kk){
      float4 a = *(const float4*)&As[kk][ty*4];
      float4 b = *(const float4*)&Bs[kk][tx*4];
      acc[0][0] += a.x*b.x; acc[0][1] += a.x*b.y; acc[0][2] += a.x*b.z; acc[0][3] += a.x*b.w;
      acc[1][0] += a.y*b.x; acc[1][1] += a.y*b.y; acc[1][2] += a.y*b.z; acc[1][3] += a.y*b.w;
      acc[2][0] += a.z*b.x; acc[2][1] += a.z*b.y; acc[2][2] += a.z*b.z; acc[2][3] += a.z*b.w;
      acc[3][0] += a.w*b.x; acc[3][1] += a.w*b.y; acc[3][2] += a.w*b.z; acc[3][3] += a.w*b.w;
    }
    __syncthreads();
  }
  #pragma unroll
  for (int i2=0;i2<4;++i2)
    #pragma unroll
    for (int j2=0;j2<4;++j2)
      C[(size_t)(m0+ty*4+i2)*ldc + n0 + tx*4 + j2] = acc[i2][j2] + bias[n0+tx*4+j2];
}

// -------- S0[b,i,j] = SCL*Sq0[b,i]·Sk0[b,j]; T0[b,k,l] = Qt0[b,k]·Kt0[b,l] --------
__global__ __launch_bounds__(256) void k_s0t0(const float* __restrict__ proj,
                                              float* __restrict__ S0,
                                              float* __restrict__ T0){
  int b = blockIdx.x, which = blockIdx.y;
  __shared__ float Lq[50][129];
  __shared__ float Lk[50][129];
  const int offq = which ? 512 : 0;
  const int offk = which ? 768 : 256;
  const float scale = which ? 1.0f : SCL;
  float* out = which ? T0 : S0;
  const int t = threadIdx.x;
  float acc[10];
  #pragma unroll
  for (int z=0;z<10;++z) acc[z]=0.f;
  for (int c0=0;c0<HSD;c0+=128){
    __syncthreads();
    for (int e=t; e<50*128; e+=256){
      int row = e>>7, c = e&127;
      Lq[row][c] = proj[(size_t)(b*SLN+row)*1280 + offq + c0 + c];
      Lk[row][c] = proj[(size_t)(b*SLN+row)*1280 + offk + c0 + c];
    }
    __syncthreads();
    #pragma unroll
    for (int z=0;z<10;++z){
      int p = t + z*256;
      if (p < 2500){
        int i = p/50, j = p - i*50;
        float s = 0.f;
        for (int c=0;c<128;++c) s += Lq[i][c]*Lk[j][c];
        acc[z] += s;
      }
    }
  }
  #pragma unroll
  for (int z=0;z<10;++z){
    int p = t + z*256;
    if (p < 2500) out[(size_t)b*2500 + p] = acc[z]*scale;
  }
}

// -------- stage C: P1[b,r,q,k] = softmax_k(S0[b,q,k]+m1[b,r,q,k]); d1 --------
__global__ __launch_bounds__(256) void k_stageC(const float* __restrict__ S0,
                                                const float* __restrict__ m1,
                                                const float* __restrict__ h0,
                                                float* __restrict__ P1,
                                                float* __restrict__ D123){
  const int blk = blockIdx.x;
  const int b = blk/SLN, r = blk - b*SLN;
  __shared__ float P[50][52];
  const int t = threadIdx.x;
  const float* mblk = m1 + (size_t)blk*2500;
  const float* s0b  = S0 + (size_t)b*2500;
  for (int e=t; e<2500; e+=256){
    int i = e/50, j = e - i*50;
    P[i][j] = s0b[e] + mblk[e];
  }
  __syncthreads();
  {
    int i = t>>2, s = t&3;
    if (i < 50){
      float mx = -1e30f;
      for (int j=s; j<50; j+=4) mx = fmaxf(mx, P[i][j]);
      mx = fmaxf(mx, __shfl_xor(mx,1,64));
      mx = fmaxf(mx, __shfl_xor(mx,2,64));
      float sm = 0.f;
      for (int j=s; j<50; j+=4){ float e_ = __expf(P[i][j]-mx); P[i][j]=e_; sm+=e_; }
      sm += __shfl_xor(sm,1,64);
      sm += __shfl_xor(sm,2,64);
      float inv = 1.0f/sm;
      for (int j=s; j<50; j+=4) P[i][j] *= inv;
    }
  }
  __syncthreads();
  float* pout = P1 + (size_t)blk*2500;
  for (int e=t; e<2500; e+=256){
    int i = e/50, j = e - i*50;
    pout[e] = P[i][j];
  }
  float acc = 0.f;
  for (int j=0;j<50;++j) acc += P[r][j]*h0[(size_t)(b*SLN+j)*HSD + t];
  D123[(size_t)blk*768 + t] = acc;   // d1
}

// -------- stage D: sim2 = W·T0·W^T + m2; P2=softmax; V2=P2·W; d2 --------
__global__ __launch_bounds__(256) void k_stageD(const float* __restrict__ P1,
                                                const float* __restrict__ T0,
                                                const float* __restrict__ m2,
                                                const float* __restrict__ h0,
                                                float* __restrict__ V2buf,
                                                float* __restrict__ D123){
  const int blk = blockIdx.x;
  const int b = blk/SLN, r = blk - b*SLN;
  __shared__ float W [50][52];
  __shared__ float Wt[50][52];
  __shared__ float T [50][52];
  __shared__ float tm[50][52];
  __shared__ float S [50][52];
  __shared__ float V2r[50];
  const int t = threadIdx.x;
  for (int e=t; e<2500; e+=256){
    int i = e/50, j = e - i*50;
    float w = P1[((size_t)(b*SLN+i)*SLN + r)*SLN + j];
    W[i][j] = w; Wt[j][i] = w;
    T[i][j] = T0[(size_t)b*2500 + e];
  }
  __syncthreads();
  for (int e=t; e<2500; e+=256){
    int i = e/50, l = e - i*50;
    float s = 0.f;
    for (int k=0;k<50;++k) s += W[i][k]*T[k][l];
    tm[i][l] = s;
  }
  __syncthreads();
  const float* mblk = m2 + (size_t)blk*2500;
  for (int e=t; e<2500; e+=256){
    int i = e/50, j = e - i*50;
    float s = 0.f;
    for (int l=0;l<50;++l) s += tm[i][l]*Wt[l][j];
    S[i][j] = s + mblk[e];
  }
  __syncthreads();
  {
    int i = t>>2, sl = t&3;
    if (i < 50){
      float mx = -1e30f;
      for (int j=sl; j<50; j+=4) mx = fmaxf(mx, S[i][j]);
      mx = fmaxf(mx, __shfl_xor(mx,1,64));
      mx = fmaxf(mx, __shfl_xor(mx,2,64));
      float sm = 0.f;
      for (int j=sl; j<50; j+=4){ float e_ = __expf(S[i][j]-mx); S[i][j]=e_; sm+=e_; }
      sm += __shfl_xor(sm,1,64);
      sm += __shfl_xor(sm,2,64);
      float inv = 1.0f/sm;
      for (int j=sl; j<50; j+=4) S[i][j] *= inv;
    }
  }
  __syncthreads();
  float* vout = V2buf + (size_t)blk*2500;
  for (int e=t; e<2500; e+=256){
    int q = e/50, j = e - q*50;
    float s = 0.f;
    for (int k=0;k<50;++k) s += S[q][k]*W[k][j];
    vout[e] = s;
    if (q == r) V2r[j] = s;
  }
  __syncthreads();
  float acc = 0.f;
  for (int j=0;j<50;++j) acc += V2r[j]*h0[(size_t)(b*SLN+j)*HSD + t];
  D123[(size_t)blk*768 + 256 + t] = acc;  // d2
}

// -------- stage E: sim3[k] = SCL*V2[b,k][i,:]·u + m3[b,i,i,k]; d3 --------
__global__ __launch_bounds__(256) void k_stageE(const float* __restrict__ q3d,
                                                const float* __restrict__ proj,
                                                const float* __restrict__ V2buf,
                                                const float* __restrict__ m3,
                                                const float* __restrict__ h0,
                                                float* __restrict__ D123){
  const int blk = blockIdx.x;
  const int b = blk/SLN, i = blk - b*SLN;
  __shared__ float qr[256];
  __shared__ float u[50];
  __shared__ float V[50][52];
  __shared__ float P3[52];
  __shared__ float w3[52];
  const int t = threadIdx.x;
  qr[t] = q3d[(size_t)blk*HSD + t];
  __syncthreads();
  if (t < 200){                       // u[j] = Ak0[b,j]·q3d[b,i]
    int j = t>>2, s = t&3;
    const float* ak = proj + (size_t)(b*SLN+j)*1280 + 1024 + s*64;
    float p = 0.f;
    for (int q=0;q<64;q+=4){
      float4 v = *(const float4*)&ak[q];
      const float* qq = &qr[s*64 + q];
      p += v.x*qq[0] + v.y*qq[1] + v.z*qq[2] + v.w*qq[3];
    }
    p += __shfl_xor(p,1,64); p += __shfl_xor(p,2,64);
    if (s==0) u[j] = p;
  }
  for (int e=t; e<2500; e+=256){
    int k = e/50, j = e - k*50;
    V[k][j] = V2buf[((size_t)(b*SLN+k)*SLN + i)*SLN + j];
  }
  __syncthreads();
  if (t < 200){                       // sim3
    int k = t>>2, s = t&3;
    float p = 0.f;
    for (int j=s; j<50; j+=4) p += V[k][j]*u[j];
    p += __shfl_xor(p,1,64); p += __shfl_xor(p,2,64);
    if (s==0) P3[k] = p*SCL + m3[((size_t)(b*SLN+i)*SLN + i)*SLN + k];
  }
  __syncthreads();
  if (t < 64){                        // softmax over 50
    float v = (t<50) ? P3[t] : -1e30f;
    float mx = v;
    for (int d=1; d<64; d<<=1) mx = fmaxf(mx, __shfl_xor(mx,d,64));
    float e_ = (t<50) ? __expf(v-mx) : 0.f;
    float sm = e_;
    for (int d=1; d<64; d<<=1) sm += __shfl_xor(sm,d,64);
    if (t<50) P3[t] = e_/sm;
  }
  __syncthreads();
  if (t < 200){                       // w3[j] = sum_k P3[k]*V[k][j]
    int j = t>>2, s = t&3;
    float p = 0.f;
    for (int k=s; k<50; k+=4) p += P3[k]*V[k][j];
    p += __shfl_xor(p,1,64); p += __shfl_xor(p,2,64);
    if (s==0) w3[j] = p;
  }
  __syncthreads();
  float acc = 0.f;
  for (int j=0;j<50;++j) acc += w3[j]*h0[(size_t)(b*SLN+j)*HSD + t];
  D123[(size_t)blk*768 + 512 + t] = acc;  // d3
}

// -------- row L2-normalize + cast to bf16; one wave per row --------
__global__ __launch_bounds__(256) void k_norm(const float* __restrict__ X,
                                              u16* __restrict__ out,
                                              int rows, int rowOffsetIn){
  int row = blockIdx.x*4 + (threadIdx.x>>6);
  if (row >= rows) return;
  int lane = threadIdx.x & 63;
  const float* x = X + (size_t)(row + rowOffsetIn)*HSD;
  float4 v = *(const float4*)&x[lane*4];
  float ss = v.x*v.x + v.y*v.y + v.z*v.z + v.w*v.w;
  for (int d=1; d<64; d<<=1) ss += __shfl_xor(ss,d,64);
  float rn = rsqrtf(ss);
  ushort4 o;
  o.x = f2bf(v.x*rn); o.y = f2bf(v.y*rn); o.z = f2bf(v.z*rn); o.w = f2bf(v.w*rn);
  *(ushort4*)&out[(size_t)row*HSD + lane*4] = o;
}

// -------- scores: out[m][n] = sum_k A[m,k]*B[n,k]  (bf16 MFMA, m97-style) --------
// 128x128 tile, BK=32, double-buffered LDS via global_load_lds w16,
// 4 waves (2x2), wave tile 64x64, single barrier per K-step with prefetch.
__global__ __launch_bounds__(256) void k_scores(const u16* __restrict__ A,
                                                const u16* __restrict__ Bn,
                                                float* __restrict__ out){
  __shared__ __align__(16) u16 As[2][4096];   // [buf][128 rows x 32 cols]
  __shared__ __align__(16) u16 Bs[2][4096];
  const int m0 = blockIdx.x*128;
  const int nb = blockIdx.y*128;
  const int t = threadIdx.x;
  const int l = t & 63, w = t >> 6;
  const int srow = l >> 2, scol = (l & 3) * 8;    // staging lane map
  const int wr = w >> 1, wc = w & 1;              // wave grid 2x2
  const int fr = l & 15, fq = l >> 4;             // fragment lane map

  f32x4 acc[4][4];
  #pragma unroll
  for (int m=0;m<4;++m)
    #pragma unroll
    for (int n=0;n<4;++n) acc[m][n] = (f32x4){0.f,0.f,0.f,0.f};

  // stage K-step ks into buffer buf: each wave fills 2 segments of 16 rows
  #define STAGE(buf, ks) do{                                                  \
    int k0_ = (ks)*32;                                                        \
    _Pragma("unroll")                                                         \
    for (int i_=0;i_<2;++i_){                                                 \
      int seg_ = w*2 + i_;                                                    \
      int row_ = seg_*16 + srow;                                              \
      const u16* ga_ = &A[(size_t)(m0+row_)*HSD + k0_ + scol];                \
      __builtin_amdgcn_global_load_lds((guint*)ga_,                           \
          (luint*)&As[buf][seg_*512], 16, 0, 0);                              \
      int brow_ = nb + row_; if (brow_ > NOUT-1) brow_ = NOUT-1;              \
      const u16* gb_ = &Bn[(size_t)brow_*HSD + k0_ + scol];                   \
      __builtin_amdgcn_global_load_lds((guint*)gb_,                           \
          (luint*)&Bs[buf][seg_*512], 16, 0, 0);                              \
    }                                                                         \
  }while(0)

  STAGE(0, 0);
  #pragma unroll
  for (int ks=0; ks<8; ++ks){
    const int cur = ks & 1;
    __syncthreads();                    // drains stage(ks) -> tile[cur] ready
    if (ks < 7) STAGE(cur^1, ks+1);     // prefetch next, hides under MFMA
    short8 af[4], bf[4];
    #pragma unroll
    for (int m=0;m<4;++m)
      af[m] = *(const short8*)&As[cur][(wr*64 + m*16 + fr)*32 + fq*8];
    #pragma unroll
    for (int n=0;n<4;++n)
      bf[n] = *(const short8*)&Bs[cur][(wc*64 + n*16 + fr)*32 + fq*8];
    #pragma unroll
    for (int m=0;m<4;++m)
      #pragma unroll
      for (int n=0;n<4;++n)
        acc[m][n] = __builtin_amdgcn_mfma_f32_16x16x32_bf16(af[m], bf[n], acc[m][n], 0, 0, 0);
  }
  #undef STAGE

  // epilogue: C/D layout col = lane&15, row = (lane>>4)*4 + reg
  const int mbase = m0 + wr*64 + fq*4;
  #pragma unroll
  for (int n=0;n<4;++n){
    int col = nb + wc*64 + n*16 + fr;
    if (col < NOUT){
      #pragma unroll
      for (int m=0;m<4;++m){
        int row = mbase + m*16;
        #pragma unroll
        for (int rr=0; rr<4; ++rr)
          out[(size_t)(row+rr)*NOUT + col] = acc[m][n][rr];
      }
    }
  }
}

extern "C" void kernel_launch(void* const* d_in, const int* in_sizes, int n_in,
                              void* d_out, int out_size, void* d_ws, size_t ws_size,
                              hipStream_t stream){
  const int*   idx   = (const int*)  d_in[0];
  const float* m1    = (const float*)d_in[1];
  const float* m2    = (const float*)d_in[2];
  const float* m3    = (const float*)d_in[3];
  const float* emb   = (const float*)d_in[4];
  const float* sq_w  = (const float*)d_in[5];
  const float* sq_b  = (const float*)d_in[6];
  const float* sk_w  = (const float*)d_in[7];
  const float* sk_b  = (const float*)d_in[8];
  const float* tq_w  = (const float*)d_in[9];
  const float* tq_b  = (const float*)d_in[10];
  const float* tk_w  = (const float*)d_in[11];
  const float* tk_b  = (const float*)d_in[12];
  const float* aq_w  = (const float*)d_in[13];
  const float* aq_b  = (const float*)d_in[14];
  const float* ak_w  = (const float*)d_in[15];
  const float* ak_b  = (const float*)d_in[16];
  const float* cat_w = (const float*)d_in[17];
  const float* cat_b = (const float*)d_in[18];
  float* out = (float*)d_out;

  float* ws = (float*)d_ws;
  size_t off = 0;
  float* h0   = ws + off; off += (size_t)MROW*HSD;
  float* proj = ws + off; off += (size_t)MROW*1280;       // Sq0|Sk0|Qt0|Kt0|Ak0
  float* Wst  = ws + off; off += (size_t)1280*HSD;
  float* bst  = ws + off; off += 1280;
  float* S0   = ws + off; off += (size_t)BSZ*2500;
  float* T0   = ws + off; off += (size_t)BSZ*2500;
  float* P1   = ws + off; off += (size_t)MROW*2500;
  float* V2   = ws + off; off += (size_t)MROW*2500;
  float* D123 = ws + off; off += (size_t)MROW*768;
  float* q3d  = ws + off; off += (size_t)MROW*HSD;
  float* a32  = ws + off; off += (size_t)MROW*HSD;
  u16*   abf  = (u16*)(ws + off); off += (size_t)MROW*HSD/2;
  u16*   bnf  = (u16*)(ws + off); off += ((size_t)NOUT*HSD+1)/2;
  (void)ws_size; (void)in_sizes; (void)n_in; (void)out_size;

  hipMemcpyAsync(Wst + 0*65536, sq_w, 65536*sizeof(float), hipMemcpyDeviceToDevice, stream);
  hipMemcpyAsync(Wst + 1*65536, sk_w, 65536*sizeof(float), hipMemcpyDeviceToDevice, stream);
  hipMemcpyAsync(Wst + 2*65536, tq_w, 65536*sizeof(float), hipMemcpyDeviceToDevice, stream);
  hipMemcpyAsync(Wst + 3*65536, tk_w, 65536*sizeof(float), hipMemcpyDeviceToDevice, stream);
  hipMemcpyAsync(Wst + 4*65536, ak_w, 65536*sizeof(float), hipMemcpyDeviceToDevice, stream);
  hipMemcpyAsync(bst + 0*256, sq_b, 256*sizeof(float), hipMemcpyDeviceToDevice, stream);
  hipMemcpyAsync(bst + 1*256, sk_b, 256*sizeof(float), hipMemcpyDeviceToDevice, stream);
  hipMemcpyAsync(bst + 2*256, tq_b, 256*sizeof(float), hipMemcpyDeviceToDevice, stream);
  hipMemcpyAsync(bst + 3*256, tk_b, 256*sizeof(float), hipMemcpyDeviceToDevice, stream);
  hipMemcpyAsync(bst + 4*256, ak_b, 256*sizeof(float), hipMemcpyDeviceToDevice, stream);

  k_gather<<<MROW, 256, 0, stream>>>(idx, emb, h0);
  k_gemm  <<<dim3(50,20), 256, 0, stream>>>(h0, HSD, Wst, HSD, bst, proj, 1280, HSD);
  k_s0t0  <<<dim3(BSZ,2), 256, 0, stream>>>(proj, S0, T0);
  k_stageC<<<MROW, 256, 0, stream>>>(S0, m1, h0, P1, D123);
  k_stageD<<<MROW, 256, 0, stream>>>(P1, T0, m2, h0, V2, D123);
  k_gemm  <<<dim3(50,4), 256, 0, stream>>>(D123+256, 768, aq_w, HSD, aq_b, q3d, HSD, HSD);
  k_stageE<<<MROW, 256, 0, stream>>>(q3d, proj, V2, m3, h0, D123);
  k_gemm  <<<dim3(50,4), 256, 0, stream>>>(D123, 768, cat_w, 768, cat_b, a32, HSD, 768);
  k_norm  <<<MROW/4, 256, 0, stream>>>(a32, abf, MROW, 0);
  k_norm  <<<10000, 256, 0, stream>>>(emb, bnf, NOUT, 1);
  k_scores<<<dim3(25,313), 256, 0, stream>>>(abf, bnf, out);
}